// Round 1
// baseline (362.726 us; speedup 1.0000x reference)
//
#include <hip/hip_runtime.h>
#include <cstddef>

// Problem: BS=8, NE=128, ENT=768, REL=768, RANK=256, OUT=256
// rows M = 8*128*128 = 131072; rel row-major [b][i][j][768]
// l1/l2: [1024][256] f32 in ws; W3b: [256][768] bf16; Web: [256][256] bf16

typedef __attribute__((ext_vector_type(8))) short short8;
typedef __attribute__((ext_vector_type(4))) float f32x4;
typedef __attribute__((ext_vector_type(4))) unsigned short us4;

__device__ __forceinline__ unsigned short f2bf(float x) {
  union { float f; unsigned u; } v; v.f = x;
  unsigned r = (v.u + 0x7FFFu + ((v.u >> 16) & 1u)) >> 16;  // RNE
  return (unsigned short)r;
}
__device__ __forceinline__ float bf2f(unsigned short h) {
  union { unsigned u; float f; } v; v.u = ((unsigned)h) << 16; return v.f;
}
__device__ __forceinline__ f32x4 mfma16(short8 a, short8 b, f32x4 c) {
  return __builtin_amdgcn_mfma_f32_16x16x32_bf16(a, b, c, 0, 0, 0);
}

// ---------------- prep: l1 = x @ W^T + bias  (8 rows/block, 256 cols) --------
__global__ __launch_bounds__(256) void prep_l12(
    const float* __restrict__ x, const float* __restrict__ W,
    const float* __restrict__ bias, float* __restrict__ outp) {
  __shared__ float xs[8][768];  // 24 KB
  const int tid = threadIdx.x;
  const int R0 = blockIdx.x * 8;  // 128 blocks -> 1024 rows
  #pragma unroll
  for (int c = 0; c < 6; ++c) {
    int f4i = c * 256 + tid;          // 1536 float4 total
    int row = f4i / 192;
    int c4 = f4i % 192;
    *(float4*)&xs[row][c4 * 4] = *(const float4*)&x[(size_t)(R0 + row) * 768 + c4 * 4];
  }
  __syncthreads();
  const int col = tid;
  const float* Wr = W + (size_t)col * 768;
  float a[8] = {0.f, 0.f, 0.f, 0.f, 0.f, 0.f, 0.f, 0.f};
  for (int k4 = 0; k4 < 192; ++k4) {
    float4 wv = *(const float4*)&Wr[k4 * 4];
    #pragma unroll
    for (int r = 0; r < 8; ++r) {
      float4 xv = *(const float4*)&xs[r][k4 * 4];
      a[r] += wv.x * xv.x + wv.y * xv.y + wv.z * xv.z + wv.w * xv.w;
    }
  }
  float bb = bias[col];
  #pragma unroll
  for (int r = 0; r < 8; ++r)
    outp[(size_t)(R0 + r) * 256 + col] = a[r] + bb;
}

// ---------------- prep: weights -> bf16 --------------------------------------
__global__ __launch_bounds__(256) void prep_conv(
    const float* __restrict__ W3, const float* __restrict__ We,
    unsigned short* __restrict__ W3b, unsigned short* __restrict__ Web) {
  int idx = blockIdx.x * 256 + threadIdx.x;  // grid 1024 -> 262144
  if (idx < 196608) W3b[idx] = f2bf(W3[idx]);
  int j = idx - 196608;
  if (j >= 0 && j < 65536) Web[j] = f2bf(We[j]);
}

// ---------------- fused main kernel ------------------------------------------
__global__ __launch_bounds__(256, 2) void fused_main(
    const float* __restrict__ rel, const float* __restrict__ l1p,
    const float* __restrict__ l2p, const unsigned short* __restrict__ W3b,
    const unsigned short* __restrict__ Web, const float* __restrict__ b3,
    const float* __restrict__ be, const float* __restrict__ lng,
    const float* __restrict__ lnb, float* __restrict__ out) {
  __shared__ union U {
    struct { unsigned short h[2][64][64]; unsigned short l[2][64][64]; } stg;  // 32 KB
    unsigned short prod[64][256];                                              // 32 KB
  } u;
  __shared__ float l1s[256], b3s[256], bes[256], gs[256], bsh[256];
  __shared__ float ps[64][4], pq[64][4], mus[64], rss[64];

  const int tid = threadIdx.x;
  const int wave = tid >> 6;
  const int lane = tid & 63;
  const int g = lane >> 4;
  const int c16 = lane & 15;

  const int R0 = blockIdx.x * 64;
  const int b = R0 >> 14;
  const int rem = R0 & 16383;
  const int i = rem >> 7;
  const int j0 = rem & 127;  // 0 or 64

  const float* relBase = rel + (size_t)((b * 128 + i) * 128 + j0) * 768;

  l1s[tid] = l1p[(b * 128 + i) * 256 + tid];
  b3s[tid] = b3[tid];
  bes[tid] = be[tid];
  gs[tid] = lng[tid];
  bsh[tid] = lnb[tid];

  // staging geometry: thread loads 4 float4 (rows srow+{0,16,32,48}, cols scol..scol+3)
  const int srow = tid >> 4;
  const int scol = (tid & 15) * 4;
  const int sswz = (srow & 7) << 3;  // same for srow+16k

  float4 rv0, rv1, rv2, rv3;
#define LOAD_REGS(KK)                                                            \
  {                                                                              \
    rv0 = *(const float4*)(relBase + (size_t)(srow) * 768 + (KK) + scol);        \
    rv1 = *(const float4*)(relBase + (size_t)(srow + 16) * 768 + (KK) + scol);   \
    rv2 = *(const float4*)(relBase + (size_t)(srow + 32) * 768 + (KK) + scol);   \
    rv3 = *(const float4*)(relBase + (size_t)(srow + 48) * 768 + (KK) + scol);   \
  }

#define CVT_STORE(BUF, ROW, V)                                                   \
  {                                                                              \
    unsigned short h0 = f2bf(V.x), h1 = f2bf(V.y), h2 = f2bf(V.z), h3 = f2bf(V.w); \
    unsigned short q0 = f2bf(V.x - bf2f(h0)), q1 = f2bf(V.y - bf2f(h1));         \
    unsigned short q2 = f2bf(V.z - bf2f(h2)), q3 = f2bf(V.w - bf2f(h3));         \
    *(us4*)&u.stg.h[BUF][ROW][scol ^ sswz] = (us4){h0, h1, h2, h3};              \
    *(us4*)&u.stg.l[BUF][ROW][scol ^ sswz] = (us4){q0, q1, q2, q3};              \
  }

#define WRITE_LDS(BUF)                                                           \
  {                                                                              \
    CVT_STORE(BUF, srow, rv0);                                                   \
    CVT_STORE(BUF, srow + 16, rv1);                                              \
    CVT_STORE(BUF, srow + 32, rv2);                                              \
    CVT_STORE(BUF, srow + 48, rv3);                                              \
  }

  f32x4 acc1[4][4] = {};

  LOAD_REGS(0);
  WRITE_LDS(0);
  __syncthreads();

  for (int ks = 0; ks < 12; ++ks) {
    const int buf = ks & 1;
    if (ks < 11) LOAD_REGS((ks + 1) * 64);
    // ---- GEMM1 compute on buf: acc1 += (rel_hi + rel_lo) @ W3b^T slice ----
    #pragma unroll
    for (int sub = 0; sub < 2; ++sub) {
      short8 ah[4], al[4];
      #pragma unroll
      for (int fm = 0; fm < 4; ++fm) {
        const int row = fm * 16 + c16;
        const int kidx = (sub * 32 + g * 8) ^ ((row & 7) << 3);
        ah[fm] = *(const short8*)&u.stg.h[buf][row][kidx];
        al[fm] = *(const short8*)&u.stg.l[buf][row][kidx];
      }
      #pragma unroll
      for (int fn = 0; fn < 4; ++fn) {
        const int n = wave * 64 + fn * 16 + c16;
        short8 bfr = *(const short8*)&W3b[(size_t)n * 768 + ks * 64 + sub * 32 + g * 8];
        #pragma unroll
        for (int fm = 0; fm < 4; ++fm) {
          acc1[fm][fn] = mfma16(ah[fm], bfr, acc1[fm][fn]);
          acc1[fm][fn] = mfma16(al[fm], bfr, acc1[fm][fn]);
        }
      }
    }
    if (ks < 11) WRITE_LDS(buf ^ 1);
    __syncthreads();
  }

  // ---- epilogue 1: prod = (l3 + b3) * l1 * l2 -> bf16 swizzled LDS ----
  #pragma unroll
  for (int fm = 0; fm < 4; ++fm) {
    #pragma unroll
    for (int r = 0; r < 4; ++r) {
      const int m = fm * 16 + g * 4 + r;
      const float* l2row = l2p + (size_t)(b * 128 + j0 + m) * 256;
      #pragma unroll
      for (int fn = 0; fn < 4; ++fn) {
        const int col = wave * 64 + fn * 16 + c16;
        float v = (acc1[fm][fn][r] + b3s[col]) * l1s[col] * l2row[col];
        u.prod[m][col ^ ((m & 7) << 3)] = f2bf(v);
      }
    }
  }
  __syncthreads();

  // ---- GEMM2: f = prod @ Web^T ----
  f32x4 acc2[4][4] = {};
  #pragma unroll
  for (int kk = 0; kk < 8; ++kk) {
    short8 a2[4];
    #pragma unroll
    for (int fm = 0; fm < 4; ++fm) {
      const int m = fm * 16 + c16;
      a2[fm] = *(const short8*)&u.prod[m][(kk * 32 + g * 8) ^ ((m & 7) << 3)];
    }
    #pragma unroll
    for (int fn = 0; fn < 4; ++fn) {
      const int n = wave * 64 + fn * 16 + c16;
      short8 bfr = *(const short8*)&Web[n * 256 + kk * 32 + g * 8];
      #pragma unroll
      for (int fm = 0; fm < 4; ++fm)
        acc2[fm][fn] = mfma16(a2[fm], bfr, acc2[fm][fn]);
    }
  }

  // ---- LN stats: per-row sum/sumsq; 16-lane shfl reduce + cross-wave LDS ----
  #pragma unroll
  for (int fm = 0; fm < 4; ++fm) {
    #pragma unroll
    for (int r = 0; r < 4; ++r) {
      float s1 = 0.f, s2 = 0.f;
      #pragma unroll
      for (int fn = 0; fn < 4; ++fn) {
        const int col = wave * 64 + fn * 16 + c16;
        float v = acc2[fm][fn][r] + bes[col];
        s1 += v; s2 += v * v;
      }
      #pragma unroll
      for (int off = 1; off < 16; off <<= 1) {
        s1 += __shfl_xor(s1, off);
        s2 += __shfl_xor(s2, off);
      }
      if (c16 == 0) {
        const int m = fm * 16 + g * 4 + r;
        ps[m][wave] = s1; pq[m][wave] = s2;
      }
    }
  }
  __syncthreads();
  if (tid < 64) {
    float s = ps[tid][0] + ps[tid][1] + ps[tid][2] + ps[tid][3];
    float q = pq[tid][0] + pq[tid][1] + pq[tid][2] + pq[tid][3];
    float mu = s * 0.00390625f;
    float var = q * 0.00390625f - mu * mu;
    mus[tid] = mu;
    rss[tid] = rsqrtf(var + 1e-6f);
  }
  __syncthreads();

  // ---- store: (f - mu)*rs*g + b ----
  #pragma unroll
  for (int fm = 0; fm < 4; ++fm) {
    #pragma unroll
    for (int r = 0; r < 4; ++r) {
      const int m = fm * 16 + g * 4 + r;
      const float mu = mus[m], rs = rss[m];
      float* orow = out + (size_t)(R0 + m) * 256;
      #pragma unroll
      for (int fn = 0; fn < 4; ++fn) {
        const int col = wave * 64 + fn * 16 + c16;
        float v = acc2[fm][fn][r] + bes[col];
        orow[col] = (v - mu) * rs * gs[col] + bsh[col];
      }
    }
  }
#undef LOAD_REGS
#undef CVT_STORE
#undef WRITE_LDS
}

extern "C" void kernel_launch(void* const* d_in, const int* in_sizes, int n_in,
                              void* d_out, int out_size, void* d_ws, size_t ws_size,
                              hipStream_t stream) {
  const float* sub = (const float*)d_in[0];
  const float* obj = (const float*)d_in[1];
  const float* rel = (const float*)d_in[2];
  const float* W1 = (const float*)d_in[3];
  const float* b1 = (const float*)d_in[4];
  const float* W2 = (const float*)d_in[5];
  const float* b2 = (const float*)d_in[6];
  const float* W3 = (const float*)d_in[7];
  const float* b3 = (const float*)d_in[8];
  const float* We = (const float*)d_in[9];
  const float* be = (const float*)d_in[10];
  const float* lng = (const float*)d_in[11];
  const float* lnb = (const float*)d_in[12];
  float* out = (float*)d_out;

  // ws layout: l1 [262144 f32] | l2 [262144 f32] | W3b [196608 bf16] | Web [65536 bf16]
  // total ~2.62 MB
  float* ws = (float*)d_ws;
  float* l1p = ws;
  float* l2p = ws + 262144;
  unsigned short* W3b = (unsigned short*)(ws + 524288);
  unsigned short* Web = W3b + 196608;

  prep_l12<<<128, 256, 0, stream>>>(sub, W1, b1, l1p);
  prep_l12<<<128, 256, 0, stream>>>(obj, W2, b2, l2p);
  prep_conv<<<1024, 256, 0, stream>>>(W3, We, W3b, Web);
  fused_main<<<2048, 256, 0, stream>>>(rel, l1p, l2p, W3b, Web, b3, be, lng, lnb, out);
}

// Round 2
// 286.066 us; speedup vs baseline: 1.2680x; 1.2680x over previous
//
#include <hip/hip_runtime.h>
#include <cstddef>

// Problem: BS=8, NE=128, ENT=768, REL=768, RANK=256, OUT=256
// rows M = 8*128*128 = 131072; rel row-major [b][i][j][768]
// l1/l2: [1024][256] f32 in ws; W3b: [256][768] bf16; Web: [256][256] bf16

typedef __attribute__((ext_vector_type(8))) short short8;
typedef __attribute__((ext_vector_type(4))) float f32x4;
typedef __attribute__((ext_vector_type(4))) unsigned short us4;

__device__ __forceinline__ unsigned short f2bf(float x) {
  union { float f; unsigned u; } v; v.f = x;
  unsigned r = (v.u + 0x7FFFu + ((v.u >> 16) & 1u)) >> 16;  // RNE
  return (unsigned short)r;
}
__device__ __forceinline__ f32x4 mfma16(short8 a, short8 b, f32x4 c) {
  return __builtin_amdgcn_mfma_f32_16x16x32_bf16(a, b, c, 0, 0, 0);
}

// ---------------- prep: l{1,2} = x @ W^T + bias  (8 rows/block) --------------
// grid 256: blocks 0..127 -> sub/W1/b1 -> l1p ; blocks 128..255 -> obj/W2/b2 -> l2p
__global__ __launch_bounds__(256) void prep_l12(
    const float* __restrict__ sub, const float* __restrict__ obj,
    const float* __restrict__ W1, const float* __restrict__ b1,
    const float* __restrict__ W2, const float* __restrict__ b2,
    float* __restrict__ l1p, float* __restrict__ l2p) {
  const int half = blockIdx.x >> 7;  // 0: sub, 1: obj
  const float* x = half ? obj : sub;
  const float* W = half ? W2 : W1;
  const float* bias = half ? b2 : b1;
  float* outp = half ? l2p : l1p;

  __shared__ float xs[8][768];  // 24 KB
  const int tid = threadIdx.x;
  const int R0 = (blockIdx.x & 127) * 8;
  #pragma unroll
  for (int c = 0; c < 6; ++c) {
    int f4i = c * 256 + tid;  // 1536 float4 total
    int row = f4i / 192;
    int c4 = f4i % 192;
    *(float4*)&xs[row][c4 * 4] = *(const float4*)&x[(size_t)(R0 + row) * 768 + c4 * 4];
  }
  __syncthreads();
  const int col = tid;
  const float* Wr = W + (size_t)col * 768;
  float a[8] = {0.f, 0.f, 0.f, 0.f, 0.f, 0.f, 0.f, 0.f};
  for (int k4 = 0; k4 < 192; ++k4) {
    float4 wv = *(const float4*)&Wr[k4 * 4];
    #pragma unroll
    for (int r = 0; r < 8; ++r) {
      float4 xv = *(const float4*)&xs[r][k4 * 4];
      a[r] += wv.x * xv.x + wv.y * xv.y + wv.z * xv.z + wv.w * xv.w;
    }
  }
  float bb = bias[col];
  #pragma unroll
  for (int r = 0; r < 8; ++r)
    outp[(size_t)(R0 + r) * 256 + col] = a[r] + bb;
}

// ---------------- prep: weights -> bf16 --------------------------------------
__global__ __launch_bounds__(256) void prep_conv(
    const float* __restrict__ W3, const float* __restrict__ We,
    unsigned short* __restrict__ W3b, unsigned short* __restrict__ Web) {
  int idx = blockIdx.x * 256 + threadIdx.x;  // grid 1024 -> 262144
  if (idx < 196608) W3b[idx] = f2bf(W3[idx]);
  int j = idx - 196608;
  if (j >= 0 && j < 65536) Web[j] = f2bf(We[j]);
}

// ---------------- fused main kernel ------------------------------------------
__global__ __launch_bounds__(256, 4) void fused_main(
    const float* __restrict__ rel, const float* __restrict__ l1p,
    const float* __restrict__ l2p, const unsigned short* __restrict__ W3b,
    const unsigned short* __restrict__ Web, const float* __restrict__ b3,
    const float* __restrict__ be, const float* __restrict__ lng,
    const float* __restrict__ lnb, float* __restrict__ out) {
  __shared__ union U {
    unsigned short stg[2][64][64];  // 16 KB (bf16 hi of rel tile, XOR-swizzled)
    unsigned short prod[64][256];   // 32 KB
  } u;
  __shared__ float l1s[256], b3s[256], bes[256], gs[256], bsh[256];
  __shared__ float ps[64][4], pq[64][4], mus[64], rss[64];

  const int tid = threadIdx.x;
  const int wave = tid >> 6;
  const int lane = tid & 63;
  const int g = lane >> 4;
  const int c16 = lane & 15;

  const int R0 = blockIdx.x * 64;
  const int b = R0 >> 14;
  const int rem = R0 & 16383;
  const int i = rem >> 7;
  const int j0 = rem & 127;  // 0 or 64

  const float* relBase = rel + (size_t)((b * 128 + i) * 128 + j0) * 768;

  l1s[tid] = l1p[(b * 128 + i) * 256 + tid];
  b3s[tid] = b3[tid];
  bes[tid] = be[tid];
  gs[tid] = lng[tid];
  bsh[tid] = lnb[tid];

  // staging geometry: thread loads 4 float4 (rows srow+{0,16,32,48}, cols scol..scol+3)
  const int srow = tid >> 4;
  const int scol = (tid & 15) * 4;
  const int sswz = (srow & 7) << 3;  // same for srow+16k

  float4 rv0, rv1, rv2, rv3;
#define LOAD_REGS(KK)                                                            \
  {                                                                              \
    rv0 = *(const float4*)(relBase + (size_t)(srow) * 768 + (KK) + scol);        \
    rv1 = *(const float4*)(relBase + (size_t)(srow + 16) * 768 + (KK) + scol);   \
    rv2 = *(const float4*)(relBase + (size_t)(srow + 32) * 768 + (KK) + scol);   \
    rv3 = *(const float4*)(relBase + (size_t)(srow + 48) * 768 + (KK) + scol);   \
  }

#define CVT_STORE(BUF, ROW, V)                                                   \
  {                                                                              \
    *(us4*)&u.stg[BUF][ROW][scol ^ sswz] =                                       \
        (us4){f2bf(V.x), f2bf(V.y), f2bf(V.z), f2bf(V.w)};                       \
  }

#define WRITE_LDS(BUF)                                                           \
  {                                                                              \
    CVT_STORE(BUF, srow, rv0);                                                   \
    CVT_STORE(BUF, srow + 16, rv1);                                              \
    CVT_STORE(BUF, srow + 32, rv2);                                              \
    CVT_STORE(BUF, srow + 48, rv3);                                              \
  }

  f32x4 acc1[4][4] = {};

  LOAD_REGS(0);
  WRITE_LDS(0);
  __syncthreads();

  for (int ks = 0; ks < 12; ++ks) {
    const int buf = ks & 1;
    if (ks < 11) LOAD_REGS((ks + 1) * 64);
    // ---- GEMM1 compute on buf: acc1 += rel_bf16 @ W3b^T slice ----
    #pragma unroll
    for (int sub = 0; sub < 2; ++sub) {
      short8 ah[4];
      #pragma unroll
      for (int fm = 0; fm < 4; ++fm) {
        const int row = fm * 16 + c16;
        const int kidx = (sub * 32 + g * 8) ^ ((row & 7) << 3);
        ah[fm] = *(const short8*)&u.stg[buf][row][kidx];
      }
      #pragma unroll
      for (int fn = 0; fn < 4; ++fn) {
        const int n = wave * 64 + fn * 16 + c16;
        short8 bfr = *(const short8*)&W3b[(size_t)n * 768 + ks * 64 + sub * 32 + g * 8];
        #pragma unroll
        for (int fm = 0; fm < 4; ++fm)
          acc1[fm][fn] = mfma16(ah[fm], bfr, acc1[fm][fn]);
      }
    }
    if (ks < 11) WRITE_LDS(buf ^ 1);
    __syncthreads();
  }

  // ---- epilogue 1: prod = (l3 + b3) * l1 * l2 -> bf16 swizzled LDS ----
  #pragma unroll
  for (int fm = 0; fm < 4; ++fm) {
    #pragma unroll
    for (int r = 0; r < 4; ++r) {
      const int m = fm * 16 + g * 4 + r;
      const float* l2row = l2p + (size_t)(b * 128 + j0 + m) * 256;
      #pragma unroll
      for (int fn = 0; fn < 4; ++fn) {
        const int col = wave * 64 + fn * 16 + c16;
        float v = (acc1[fm][fn][r] + b3s[col]) * l1s[col] * l2row[col];
        u.prod[m][col ^ ((m & 7) << 3)] = f2bf(v);
      }
    }
  }
  __syncthreads();

  // ---- GEMM2: f = prod @ Web^T ----
  f32x4 acc2[4][4] = {};
  #pragma unroll
  for (int kk = 0; kk < 8; ++kk) {
    short8 a2[4];
    #pragma unroll
    for (int fm = 0; fm < 4; ++fm) {
      const int m = fm * 16 + c16;
      a2[fm] = *(const short8*)&u.prod[m][(kk * 32 + g * 8) ^ ((m & 7) << 3)];
    }
    #pragma unroll
    for (int fn = 0; fn < 4; ++fn) {
      const int n = wave * 64 + fn * 16 + c16;
      short8 bfr = *(const short8*)&Web[n * 256 + kk * 32 + g * 8];
      #pragma unroll
      for (int fm = 0; fm < 4; ++fm)
        acc2[fm][fn] = mfma16(a2[fm], bfr, acc2[fm][fn]);
    }
  }

  // ---- LN stats: per-row sum/sumsq; 16-lane shfl reduce + cross-wave LDS ----
  #pragma unroll
  for (int fm = 0; fm < 4; ++fm) {
    #pragma unroll
    for (int r = 0; r < 4; ++r) {
      float s1 = 0.f, s2 = 0.f;
      #pragma unroll
      for (int fn = 0; fn < 4; ++fn) {
        const int col = wave * 64 + fn * 16 + c16;
        float v = acc2[fm][fn][r] + bes[col];
        s1 += v; s2 += v * v;
      }
      #pragma unroll
      for (int off = 1; off < 16; off <<= 1) {
        s1 += __shfl_xor(s1, off);
        s2 += __shfl_xor(s2, off);
      }
      if (c16 == 0) {
        const int m = fm * 16 + g * 4 + r;
        ps[m][wave] = s1; pq[m][wave] = s2;
      }
    }
  }
  __syncthreads();
  if (tid < 64) {
    float s = ps[tid][0] + ps[tid][1] + ps[tid][2] + ps[tid][3];
    float q = pq[tid][0] + pq[tid][1] + pq[tid][2] + pq[tid][3];
    float mu = s * 0.00390625f;
    float var = q * 0.00390625f - mu * mu;
    mus[tid] = mu;
    rss[tid] = rsqrtf(var + 1e-6f);
  }
  __syncthreads();

  // ---- store: (f - mu)*rs*g + b ----
  #pragma unroll
  for (int fm = 0; fm < 4; ++fm) {
    #pragma unroll
    for (int r = 0; r < 4; ++r) {
      const int m = fm * 16 + g * 4 + r;
      const float mu = mus[m], rs = rss[m];
      float* orow = out + (size_t)(R0 + m) * 256;
      #pragma unroll
      for (int fn = 0; fn < 4; ++fn) {
        const int col = wave * 64 + fn * 16 + c16;
        float v = acc2[fm][fn][r] + bes[col];
        orow[col] = (v - mu) * rs * gs[col] + bsh[col];
      }
    }
  }
#undef LOAD_REGS
#undef CVT_STORE
#undef WRITE_LDS
}

extern "C" void kernel_launch(void* const* d_in, const int* in_sizes, int n_in,
                              void* d_out, int out_size, void* d_ws, size_t ws_size,
                              hipStream_t stream) {
  const float* sub = (const float*)d_in[0];
  const float* obj = (const float*)d_in[1];
  const float* rel = (const float*)d_in[2];
  const float* W1 = (const float*)d_in[3];
  const float* b1 = (const float*)d_in[4];
  const float* W2 = (const float*)d_in[5];
  const float* b2 = (const float*)d_in[6];
  const float* W3 = (const float*)d_in[7];
  const float* b3 = (const float*)d_in[8];
  const float* We = (const float*)d_in[9];
  const float* be = (const float*)d_in[10];
  const float* lng = (const float*)d_in[11];
  const float* lnb = (const float*)d_in[12];
  float* out = (float*)d_out;

  // ws layout: l1 [262144 f32] | l2 [262144 f32] | W3b [196608 bf16] | Web [65536 bf16]
  float* ws = (float*)d_ws;
  float* l1p = ws;
  float* l2p = ws + 262144;
  unsigned short* W3b = (unsigned short*)(ws + 524288);
  unsigned short* Web = W3b + 196608;

  prep_l12<<<256, 256, 0, stream>>>(sub, obj, W1, b1, W2, b2, l1p, l2p);
  prep_conv<<<1024, 256, 0, stream>>>(W3, We, W3b, Web);
  fused_main<<<2048, 256, 0, stream>>>(rel, l1p, l2p, W3b, Web, b3, be, lng, lnb, out);
}

// Round 3
// 224.760 us; speedup vs baseline: 1.6138x; 1.2728x over previous
//
#include <hip/hip_runtime.h>
#include <hip/hip_bf16.h>
#include <cstddef>

// Problem: BS=8, NE=128, ENT=768, REL=768, RANK=256, OUT=256
// rows M = 8*128*128 = 131072; rel row-major [b][i][j][768]
// ws: l1 [1024*256 f32] | l2 [1024*256 f32] | W3g [196608 bf16 fragmented] | Weg [65536 bf16 fragmented]
// Fragment layout for B panels: flat = ((kq*256 + n)*4 + g)*8 + e, kq=k/32, g=(k/8)%4, e=k%8
// -> a wave's B-fragment load (16 n x 4 g x 8 e) is one contiguous 1-KB dwordx4.

typedef __attribute__((ext_vector_type(8))) short short8;
typedef __attribute__((ext_vector_type(4))) float f32x4;

__device__ __forceinline__ unsigned short f2bf(float x) {
  union { float f; unsigned u; } v; v.f = x;
  unsigned r = (v.u + 0x7FFFu + ((v.u >> 16) & 1u)) >> 16;  // RNE
  return (unsigned short)r;
}
__device__ __forceinline__ unsigned short cvt1(float x) {
  return __bfloat16_as_ushort(__float2bfloat16(x));  // RNE; compiler pairs to v_cvt_pk_bf16_f32
}
__device__ __forceinline__ f32x4 mfma16(short8 a, short8 b, f32x4 c) {
  return __builtin_amdgcn_mfma_f32_16x16x32_bf16(a, b, c, 0, 0, 0);
}
__device__ __forceinline__ void gload_lds16(const float* g, float* l) {
  __builtin_amdgcn_global_load_lds((__attribute__((address_space(1))) void*)(g),
                                   (__attribute__((address_space(3))) void*)(l), 16, 0, 0);
}

// read 8 f32 from swizzled LDS tile and convert to bf16 frag
__device__ __forceinline__ short8 frag_cvt(const float* p) {
  f32x4 lo = *(const f32x4*)p;
  f32x4 hi = *(const f32x4*)(p + 4);
  short8 s;
  s[0] = (short)cvt1(lo[0]); s[1] = (short)cvt1(lo[1]);
  s[2] = (short)cvt1(lo[2]); s[3] = (short)cvt1(lo[3]);
  s[4] = (short)cvt1(hi[0]); s[5] = (short)cvt1(hi[1]);
  s[6] = (short)cvt1(hi[2]); s[7] = (short)cvt1(hi[3]);
  return s;
}

// ---------------- prep: l{1,2} = x @ W^T + bias  (8 rows/block) --------------
__global__ __launch_bounds__(256) void prep_l12(
    const float* __restrict__ sub, const float* __restrict__ obj,
    const float* __restrict__ W1, const float* __restrict__ b1,
    const float* __restrict__ W2, const float* __restrict__ b2,
    float* __restrict__ l1p, float* __restrict__ l2p) {
  const int half = blockIdx.x >> 7;  // 0: sub, 1: obj
  const float* x = half ? obj : sub;
  const float* W = half ? W2 : W1;
  const float* bias = half ? b2 : b1;
  float* outp = half ? l2p : l1p;

  __shared__ float xs[8][768];
  const int tid = threadIdx.x;
  const int R0 = (blockIdx.x & 127) * 8;
  #pragma unroll
  for (int c = 0; c < 6; ++c) {
    int f4i = c * 256 + tid;
    int row = f4i / 192;
    int c4 = f4i % 192;
    *(float4*)&xs[row][c4 * 4] = *(const float4*)&x[(size_t)(R0 + row) * 768 + c4 * 4];
  }
  __syncthreads();
  const int col = tid;
  const float* Wr = W + (size_t)col * 768;
  float a[8] = {0.f, 0.f, 0.f, 0.f, 0.f, 0.f, 0.f, 0.f};
  for (int k4 = 0; k4 < 192; ++k4) {
    float4 wv = *(const float4*)&Wr[k4 * 4];
    #pragma unroll
    for (int r = 0; r < 8; ++r) {
      float4 xv = *(const float4*)&xs[r][k4 * 4];
      a[r] += wv.x * xv.x + wv.y * xv.y + wv.z * xv.z + wv.w * xv.w;
    }
  }
  float bb = bias[col];
  #pragma unroll
  for (int r = 0; r < 8; ++r)
    outp[(size_t)(R0 + r) * 256 + col] = a[r] + bb;
}

// ---------------- prep: weights -> bf16 in fragment-major layout -------------
__global__ __launch_bounds__(256) void prep_conv(
    const float* __restrict__ W3, const float* __restrict__ We,
    unsigned short* __restrict__ W3g, unsigned short* __restrict__ Weg) {
  int idx = blockIdx.x * 256 + threadIdx.x;  // grid 1024 -> 262144
  if (idx < 196608) {
    int n = idx / 768, k = idx % 768;
    int f = ((k >> 5) * 256 + n) * 32 + ((k >> 3) & 3) * 8 + (k & 7);
    W3g[f] = f2bf(W3[idx]);
  }
  int j = idx - 196608;
  if (j >= 0 && j < 65536) {
    int n = j / 256, k = j % 256;
    int f = ((k >> 5) * 256 + n) * 32 + ((k >> 3) & 3) * 8 + (k & 7);
    Weg[f] = f2bf(We[j]);
  }
}

// ---------------- fused main kernel ------------------------------------------
__global__ __launch_bounds__(256, 4) void fused_main(
    const float* __restrict__ rel, const float* __restrict__ l1p,
    const float* __restrict__ l2p, const unsigned short* __restrict__ W3g,
    const unsigned short* __restrict__ Weg, const float* __restrict__ b3,
    const float* __restrict__ be, const float* __restrict__ lng,
    const float* __restrict__ lnb, float* __restrict__ out) {
  __shared__ union U {
    float stgf[2][4096];            // 2 x (64 rows x 64 f32), source-swizzled; 32 KB
    unsigned short prod[64][256];   // 32 KB
  } u;
  __shared__ float l1s[256], b3s[256], bes[256], gs[256], bsh[256];
  __shared__ float ps[64][4], pq[64][4], mus[64], rss[64];

  const int tid = threadIdx.x;
  const int wave = tid >> 6;
  const int lane = tid & 63;
  const int g = lane >> 4;
  const int c16 = lane & 15;

  const int R0 = blockIdx.x * 64;
  const int b = R0 >> 14;
  const int rem = R0 & 16383;
  const int i = rem >> 7;
  const int j0 = rem & 127;  // 0 or 64

  const float* relBase = rel + (size_t)((b * 128 + i) * 128 + j0) * 768;

  l1s[tid] = l1p[(b * 128 + i) * 256 + tid];
  b3s[tid] = b3[tid];
  bes[tid] = be[tid];
  gs[tid] = lng[tid];
  bsh[tid] = lnb[tid];

  // ---- staging geometry (T21): linear LDS dest, inverse-swizzled global src.
  // LDS[r][u] (16B units u=0..15 per 256-B row) holds G[r][u ^ ((r&7)<<1)].
  // Wave covers chunks q=0..3 (4 rows each): rows wave*16 .. wave*16+15.
  const int lq = lane >> 4;   // row within chunk
  const int u16 = lane & 15;  // 16B unit within row
  const float* gsrc[4];
  #pragma unroll
  for (int q = 0; q < 4; ++q) {
    int r = (wave * 4 + q) * 4 + lq;
    int ug = u16 ^ ((r & 7) << 1);
    gsrc[q] = relBase + (size_t)r * 768 + ug * 4;
  }

#define ISSUE(BUF, KS)                                                         \
  {                                                                            \
    _Pragma("unroll") for (int q = 0; q < 4; ++q)                              \
        gload_lds16(gsrc[q] + (KS) * 64, &u.stgf[BUF][(wave * 4 + q) * 256]);  \
  }

  f32x4 acc1[4][4] = {};

  auto compute_tile = [&](int buf, int ks) {
    const float* base = &u.stgf[buf][0];
    #pragma unroll
    for (int sub = 0; sub < 2; ++sub) {
      short8 ah[4];
      #pragma unroll
      for (int fm = 0; fm < 4; ++fm) {
        const int r = fm * 16 + c16;
        const int gg = sub * 4 + g;
        ah[fm] = frag_cvt(base + r * 64 + ((gg ^ (r & 7)) << 3));
      }
      #pragma unroll
      for (int fn = 0; fn < 4; ++fn) {
        const int n = wave * 64 + fn * 16 + c16;
        short8 bfr = *(const short8*)&W3g[(((ks * 2 + sub) * 256 + n) * 4 + g) * 8];
        #pragma unroll
        for (int fm = 0; fm < 4; ++fm)
          acc1[fm][fn] = mfma16(ah[fm], bfr, acc1[fm][fn]);
      }
    }
  };

  __syncthreads();   // l1s etc. visible
  ISSUE(0, 0);

  for (int ks = 0; ks < 11; ++ks) {
    const int buf = ks & 1;
    ISSUE(buf ^ 1, ks + 1);
    asm volatile("s_waitcnt vmcnt(4)" ::: "memory");  // tile ks landed (my 4 oldest)
    __builtin_amdgcn_s_barrier();                     // all waves' tile ks landed
    __builtin_amdgcn_sched_barrier(0);
    compute_tile(buf, ks);
    __builtin_amdgcn_sched_barrier(0);
    __builtin_amdgcn_s_barrier();                     // all waves done reading buf
  }
  asm volatile("s_waitcnt vmcnt(0)" ::: "memory");
  __builtin_amdgcn_s_barrier();
  __builtin_amdgcn_sched_barrier(0);
  compute_tile(1, 11);
  __builtin_amdgcn_sched_barrier(0);
  __builtin_amdgcn_s_barrier();

  // ---- epilogue 1: prod = (l3 + b3) * l1 * l2 -> bf16 swizzled LDS ----
  #pragma unroll
  for (int fm = 0; fm < 4; ++fm) {
    #pragma unroll
    for (int r = 0; r < 4; ++r) {
      const int m = fm * 16 + g * 4 + r;
      const float* l2row = l2p + (size_t)(b * 128 + j0 + m) * 256;
      #pragma unroll
      for (int fn = 0; fn < 4; ++fn) {
        const int col = wave * 64 + fn * 16 + c16;
        float v = (acc1[fm][fn][r] + b3s[col]) * l1s[col] * l2row[col];
        u.prod[m][col ^ ((m & 7) << 3)] = f2bf(v);
      }
    }
  }
  __syncthreads();

  // ---- GEMM2: f = prod @ Web^T (Weg fragment-major) ----
  f32x4 acc2[4][4] = {};
  #pragma unroll
  for (int kk = 0; kk < 8; ++kk) {
    short8 a2[4];
    #pragma unroll
    for (int fm = 0; fm < 4; ++fm) {
      const int m = fm * 16 + c16;
      a2[fm] = *(const short8*)&u.prod[m][(kk * 32 + g * 8) ^ ((m & 7) << 3)];
    }
    #pragma unroll
    for (int fn = 0; fn < 4; ++fn) {
      const int n = wave * 64 + fn * 16 + c16;
      short8 bfr = *(const short8*)&Weg[((kk * 256 + n) * 4 + g) * 8];
      #pragma unroll
      for (int fm = 0; fm < 4; ++fm)
        acc2[fm][fn] = mfma16(a2[fm], bfr, acc2[fm][fn]);
    }
  }

  // ---- LN stats ----
  #pragma unroll
  for (int fm = 0; fm < 4; ++fm) {
    #pragma unroll
    for (int r = 0; r < 4; ++r) {
      float s1 = 0.f, s2 = 0.f;
      #pragma unroll
      for (int fn = 0; fn < 4; ++fn) {
        const int col = wave * 64 + fn * 16 + c16;
        float v = acc2[fm][fn][r] + bes[col];
        s1 += v; s2 += v * v;
      }
      #pragma unroll
      for (int off = 1; off < 16; off <<= 1) {
        s1 += __shfl_xor(s1, off);
        s2 += __shfl_xor(s2, off);
      }
      if (c16 == 0) {
        const int m = fm * 16 + g * 4 + r;
        ps[m][wave] = s1; pq[m][wave] = s2;
      }
    }
  }
  __syncthreads();
  if (tid < 64) {
    float s = ps[tid][0] + ps[tid][1] + ps[tid][2] + ps[tid][3];
    float q = pq[tid][0] + pq[tid][1] + pq[tid][2] + pq[tid][3];
    float mu = s * 0.00390625f;
    float var = q * 0.00390625f - mu * mu;
    mus[tid] = mu;
    rss[tid] = rsqrtf(var + 1e-6f);
  }
  __syncthreads();

  // ---- store ----
  #pragma unroll
  for (int fm = 0; fm < 4; ++fm) {
    #pragma unroll
    for (int r = 0; r < 4; ++r) {
      const int m = fm * 16 + g * 4 + r;
      const float mu = mus[m], rs = rss[m];
      float* orow = out + (size_t)(R0 + m) * 256;
      #pragma unroll
      for (int fn = 0; fn < 4; ++fn) {
        const int col = wave * 64 + fn * 16 + c16;
        float v = acc2[fm][fn][r] + bes[col];
        orow[col] = (v - mu) * rs * gs[col] + bsh[col];
      }
    }
  }
#undef ISSUE
}

extern "C" void kernel_launch(void* const* d_in, const int* in_sizes, int n_in,
                              void* d_out, int out_size, void* d_ws, size_t ws_size,
                              hipStream_t stream) {
  const float* sub = (const float*)d_in[0];
  const float* obj = (const float*)d_in[1];
  const float* rel = (const float*)d_in[2];
  const float* W1 = (const float*)d_in[3];
  const float* b1 = (const float*)d_in[4];
  const float* W2 = (const float*)d_in[5];
  const float* b2 = (const float*)d_in[6];
  const float* W3 = (const float*)d_in[7];
  const float* b3 = (const float*)d_in[8];
  const float* We = (const float*)d_in[9];
  const float* be = (const float*)d_in[10];
  const float* lng = (const float*)d_in[11];
  const float* lnb = (const float*)d_in[12];
  float* out = (float*)d_out;

  float* ws = (float*)d_ws;
  float* l1p = ws;
  float* l2p = ws + 262144;
  unsigned short* W3g = (unsigned short*)(ws + 524288);
  unsigned short* Weg = W3g + 196608;

  prep_l12<<<256, 256, 0, stream>>>(sub, obj, W1, b1, W2, b2, l1p, l2p);
  prep_conv<<<1024, 256, 0, stream>>>(W3, We, W3g, Weg);
  fused_main<<<2048, 256, 0, stream>>>(rel, l1p, l2p, W3g, Weg, b3, be, lng, lnb, out);
}